// Round 1
// baseline (556.055 us; speedup 1.0000x reference)
//
#include <hip/hip_runtime.h>
#include <math.h>

// Problem constants
#define NPIX   131072      // 32*64*64 pixels
#define KCODES 512
#define DIM    64
#define HW     4096        // 64*64
#define CHW    262144      // 64*4096
#define TILE_K 128
#define NTILES 4

// Output layout (floats, concatenated in reference return order)
// [0]            quant_loss (1)
// [1]            quantized  (8388608)   [B,C,H,W]
// [8388609]      perplexity (1)
// [8388610]      encodings  (67108864)  [N,512]
// [75497474]     idx        (131072)
#define O_Q    1ll
#define O_PERP 8388609ll
#define O_ENC  8388610ll
#define O_IDX  75497474ll

// ws layout (floats): [0] loss accum, [1..512] counts (u32), [513..1024] esq

// Replicate numpy pairwise_sum of x**2 for n=64:
// 8 accumulators over stride-8 slices, combined ((r0+r1)+(r2+r3))+((r4+r5)+(r6+r7)).
// contract(off) so square (mul) and add round separately, exactly like np's
// materialized z**2 array followed by pairwise add.
__device__ __forceinline__ float np_sumsq64(const float (&x)[64]) {
#pragma clang fp contract(off)
  float r0 = x[0]*x[0], r1 = x[1]*x[1], r2 = x[2]*x[2], r3 = x[3]*x[3];
  float r4 = x[4]*x[4], r5 = x[5]*x[5], r6 = x[6]*x[6], r7 = x[7]*x[7];
#pragma unroll
  for (int i = 8; i < 64; i += 8) {
    r0 += x[i+0]*x[i+0];
    r1 += x[i+1]*x[i+1];
    r2 += x[i+2]*x[i+2];
    r3 += x[i+3]*x[i+3];
    r4 += x[i+4]*x[i+4];
    r5 += x[i+5]*x[i+5];
    r6 += x[i+6]*x[i+6];
    r7 += x[i+7]*x[i+7];
  }
  return ((r0+r1)+(r2+r3))+((r4+r5)+(r6+r7));
}

// Prep: zero loss accumulator + counts, compute esq[k] (np-pairwise) into ws.
__global__ void vq_prep(const float* __restrict__ emb, float* __restrict__ ws) {
  const int t = threadIdx.x;  // 512 threads
  if (t == 0) ws[0] = 0.0f;
  ((unsigned*)ws)[1 + t] = 0u;
  float x[64];
  const float* e = emb + t * DIM;
#pragma unroll
  for (int d = 0; d < 64; ++d) x[d] = e[d];
  ws[513 + t] = np_sumsq64(x);
}

// Main: one thread handles 2 pixels. Embedding staged in LDS in 4 tiles of 128
// codes (32KB). dist = (zsq + esq[k]) - 2*dot with dot an ascending-k fp32 FMA
// chain (mirrors OpenBLAS sgemm accumulation). Strict < keeps lowest index on
// fp32 ties, matching np.argmin.
__global__ __launch_bounds__(256, 1) void vq_main(
    const float* __restrict__ z, const float* __restrict__ emb,
    float* __restrict__ out, float* __restrict__ ws)
{
  __shared__ float et[TILE_K * DIM];     // 32 KB embedding tile
  __shared__ float es[TILE_K];           // esq tile
  __shared__ unsigned hist[KCODES];      // per-block histogram
  __shared__ unsigned short ridx[512];   // per-row argmin for encodings write
  __shared__ float wsum[4];

  const int t   = threadIdx.x;
  const int blk = blockIdx.x;
  const int n0  = blk * 512 + t;
  const int n1  = n0 + 256;

  hist[t] = 0u;
  hist[t + 256] = 0u;

  // Load both pixels' z vectors into registers ([B,C,H,W]: stride HW over c)
  float za[DIM], zb[DIM];
  {
    const float* p0 = z + (size_t)(n0 >> 12) * CHW + (n0 & 4095);
    const float* p1 = z + (size_t)(n1 >> 12) * CHW + (n1 & 4095);
#pragma unroll
    for (int d = 0; d < DIM; ++d) {
      za[d] = p0[(size_t)d * HW];
      zb[d] = p1[(size_t)d * HW];
    }
  }
  const float zsqa = np_sumsq64(za);
  const float zsqb = np_sumsq64(zb);

  const float* esq_g = ws + 513;
  float best0 = INFINITY, best1 = INFINITY;
  int bi0 = 0, bi1 = 0;

  for (int tile = 0; tile < NTILES; ++tile) {
    __syncthreads();
    {
      const float4* src = (const float4*)(emb + (size_t)tile * TILE_K * DIM);
      float4* dst = (float4*)et;
#pragma unroll
      for (int i = 0; i < 8; ++i) dst[t + 256 * i] = src[t + 256 * i];
      if (t < TILE_K) es[t] = esq_g[tile * TILE_K + t];
    }
    __syncthreads();

#pragma unroll 2
    for (int kk = 0; kk < TILE_K; ++kk) {
      const float4* er = (const float4*)(et + kk * DIM);
      float d0 = 0.0f, d1 = 0.0f;
#pragma unroll
      for (int q = 0; q < 16; ++q) {
        const float4 e4 = er[q];
        d0 = fmaf(za[4*q+0], e4.x, d0);
        d0 = fmaf(za[4*q+1], e4.y, d0);
        d0 = fmaf(za[4*q+2], e4.z, d0);
        d0 = fmaf(za[4*q+3], e4.w, d0);
        d1 = fmaf(zb[4*q+0], e4.x, d1);
        d1 = fmaf(zb[4*q+1], e4.y, d1);
        d1 = fmaf(zb[4*q+2], e4.z, d1);
        d1 = fmaf(zb[4*q+3], e4.w, d1);
      }
      const int k = tile * TILE_K + kk;
      const float eq = es[kk];
      const float dist0 = (zsqa + eq) - 2.0f * d0;  // 2*dot exact; same as np rounding
      const float dist1 = (zsqb + eq) - 2.0f * d1;
      if (dist0 < best0) { best0 = dist0; bi0 = k; }
      if (dist1 < best1) { best1 = dist1; bi1 = k; }
    }
  }

  // ---- epilogue ----
  atomicAdd(&hist[bi0], 1u);
  atomicAdd(&hist[bi1], 1u);
  ridx[t]       = (unsigned short)bi0;
  ridx[t + 256] = (unsigned short)bi1;

  out[O_IDX + n0] = (float)bi0;
  out[O_IDX + n1] = (float)bi1;

  // quantized output (transposed back to [B,C,H,W]) + loss partial
  float lsum = 0.0f;
  {
    const float* e0 = emb + (size_t)bi0 * DIM;
    float* q0 = out + O_Q + (size_t)(n0 >> 12) * CHW + (n0 & 4095);
#pragma unroll
    for (int d = 0; d < DIM; ++d) {
      const float ev = e0[d];
      const float df = ev - za[d];
      lsum = fmaf(df, df, lsum);
      q0[(size_t)d * HW] = ev;
    }
    const float* e1 = emb + (size_t)bi1 * DIM;
    float* q1 = out + O_Q + (size_t)(n1 >> 12) * CHW + (n1 & 4095);
#pragma unroll
    for (int d = 0; d < DIM; ++d) {
      const float ev = e1[d];
      const float df = ev - zb[d];
      lsum = fmaf(df, df, lsum);
      q1[(size_t)d * HW] = ev;
    }
  }
  // wave + block reduce of loss
#pragma unroll
  for (int off = 32; off > 0; off >>= 1) lsum += __shfl_down(lsum, off, 64);
  if ((t & 63) == 0) wsum[t >> 6] = lsum;
  __syncthreads();  // also publishes hist[] and ridx[]
  if (t == 0) atomicAdd(ws, (wsum[0] + wsum[1]) + (wsum[2] + wsum[3]));

  unsigned* counts = (unsigned*)ws + 1;
  atomicAdd(&counts[t],       hist[t]);
  atomicAdd(&counts[t + 256], hist[t + 256]);

  // encodings: 512 rows x 512 floats per block, one-hot. float2 stores
  // (O_ENC is only 8-byte aligned). Coalesced: consecutive threads write
  // consecutive float2.
  float2* enc = (float2*)(out + O_ENC) + (size_t)blk * (512 * 256);
  for (int i = t; i < 512 * 256; i += 256) {
    const int r  = i >> 8;        // row (local pixel)
    const int c2 = i & 255;       // float2 index within row
    const unsigned bi = ridx[r];
    float2 v = make_float2(0.0f, 0.0f);
    if ((int)(bi >> 1) == c2) {
      if (bi & 1) v.y = 1.0f; else v.x = 1.0f;
    }
    enc[i] = v;
  }
}

// Finalize: perplexity from counts (exact: counts/2^17), loss mean.
__global__ void vq_fin(float* __restrict__ out, const float* __restrict__ ws) {
  __shared__ float red[8];
  const int t = threadIdx.x;  // 512
  const unsigned* counts = (const unsigned*)ws + 1;
  const float p = (float)counts[t] * (1.0f / 131072.0f);
  float h = p * logf(p + 1e-10f);
#pragma unroll
  for (int off = 32; off > 0; off >>= 1) h += __shfl_down(h, off, 64);
  if ((t & 63) == 0) red[t >> 6] = h;
  __syncthreads();
  if (t == 0) {
    float H = 0.0f;
#pragma unroll
    for (int w = 0; w < 8; ++w) H += red[w];
    out[O_PERP] = expf(-H);
    out[0] = 1.25f * ws[0] * (1.0f / 8388608.0f);
  }
}

extern "C" void kernel_launch(void* const* d_in, const int* in_sizes, int n_in,
                              void* d_out, int out_size, void* d_ws, size_t ws_size,
                              hipStream_t stream) {
  const float* z   = (const float*)d_in[0];
  const float* emb = (const float*)d_in[1];
  float* out = (float*)d_out;
  float* ws  = (float*)d_ws;

  vq_prep<<<1, 512, 0, stream>>>(emb, ws);
  vq_main<<<256, 256, 0, stream>>>(z, emb, out, ws);
  vq_fin<<<1, 512, 0, stream>>>(out, ws);
}

// Round 2
// 541.751 us; speedup vs baseline: 1.0264x; 1.0264x over previous
//
#include <hip/hip_runtime.h>
#include <math.h>

// Problem constants
#define NPIX   131072      // 32*64*64 pixels
#define KCODES 512
#define DIM    64
#define HW     4096        // 64*64
#define CHW    262144      // 64*4096

// Output layout (floats, concatenated in reference return order)
// [0]            quant_loss (1)
// [1]            quantized  (8388608)   [B,C,H,W]
// [8388609]      perplexity (1)
// [8388610]      encodings  (67108864)  [N,512]
// [75497474]     idx        (131072)
#define O_Q    1ll
#define O_PERP 8388609ll
#define O_ENC  8388610ll
#define O_IDX  75497474ll

// ws layout (floats): [0] loss accum, [1..512] counts (u32), [513..1024] esq

// Replicate numpy pairwise_sum of x**2 for n=64:
// 8 accumulators over stride-8 slices, combined ((r0+r1)+(r2+r3))+((r4+r5)+(r6+r7)).
__device__ __forceinline__ float np_sumsq64(const float (&x)[64]) {
#pragma clang fp contract(off)
  float r0 = x[0]*x[0], r1 = x[1]*x[1], r2 = x[2]*x[2], r3 = x[3]*x[3];
  float r4 = x[4]*x[4], r5 = x[5]*x[5], r6 = x[6]*x[6], r7 = x[7]*x[7];
#pragma unroll
  for (int i = 8; i < 64; i += 8) {
    r0 += x[i+0]*x[i+0];
    r1 += x[i+1]*x[i+1];
    r2 += x[i+2]*x[i+2];
    r3 += x[i+3]*x[i+3];
    r4 += x[i+4]*x[i+4];
    r5 += x[i+5]*x[i+5];
    r6 += x[i+6]*x[i+6];
    r7 += x[i+7]*x[i+7];
  }
  return ((r0+r1)+(r2+r3))+((r4+r5)+(r6+r7));
}

// Prep: zero loss accumulator + counts, compute esq[k] (np-pairwise) into ws.
__global__ void vq_prep(const float* __restrict__ emb, float* __restrict__ ws) {
  const int t = threadIdx.x;  // 512 threads
  if (t == 0) ws[0] = 0.0f;
  ((unsigned*)ws)[1 + t] = 0u;
  float x[64];
  const float* e = emb + t * DIM;
#pragma unroll
  for (int d = 0; d < 64; ++d) x[d] = e[d];
  ws[513 + t] = np_sumsq64(x);
}

// Main: one thread = one pixel. Embedding rows are WAVE-UNIFORM in the k-loop,
// so they're read directly from global with uniform indices -> compiler emits
// s_load into SGPRs (SMEM pipe), freeing the LDS pipe entirely. The dot is a
// single ascending-k fp32 FMA chain (mirrors OpenBLAS sgemm accumulation);
// strict < keeps lowest index on fp32 ties, matching np.argmin.
__global__ __launch_bounds__(256) void vq_main(
    const float* __restrict__ z, const float* __restrict__ emb,
    float* __restrict__ out, float* __restrict__ ws)
{
  __shared__ unsigned hist[KCODES];     // per-block histogram
  __shared__ unsigned short ridx[256];  // per-row argmin for encodings write
  __shared__ float wsum[4];

  const int t   = threadIdx.x;
  const int blk = blockIdx.x;
  const int n   = blk * 256 + t;        // pixel id, grid = 512 blocks

  hist[t] = 0u;
  hist[t + 256] = 0u;

  // Load this pixel's z vector into registers ([B,C,H,W]: stride HW over c)
  float za[DIM];
  {
    const float* p0 = z + (size_t)(n >> 12) * CHW + (n & 4095);
#pragma unroll
    for (int d = 0; d < DIM; ++d) za[d] = p0[(size_t)d * HW];
  }
  const float zsqa = np_sumsq64(za);

  const float* __restrict__ esq = ws + 513;
  float best = INFINITY;
  int bi = 0;

  for (int k = 0; k < KCODES; ++k) {
    const float* __restrict__ e = emb + (k << 6);  // wave-uniform -> s_load
    float dot = 0.0f;
#pragma unroll
    for (int d = 0; d < DIM; ++d) dot = fmaf(za[d], e[d], dot);
    const float dist = (zsqa + esq[k]) - 2.0f * dot;  // same rounding as np
    if (dist < best) { best = dist; bi = k; }
  }

  // ---- epilogue ----
  atomicAdd(&hist[bi], 1u);
  ridx[t] = (unsigned short)bi;
  out[O_IDX + n] = (float)bi;

  // quantized output (transposed back to [B,C,H,W]) + loss partial
  float lsum = 0.0f;
  {
    const float* e0 = emb + ((size_t)bi << 6);
    float* q0 = out + O_Q + (size_t)(n >> 12) * CHW + (n & 4095);
#pragma unroll
    for (int d = 0; d < DIM; ++d) {
      const float ev = e0[d];
      const float df = ev - za[d];
      lsum = fmaf(df, df, lsum);
      q0[(size_t)d * HW] = ev;
    }
  }
  // wave + block reduce of loss
#pragma unroll
  for (int off = 32; off > 0; off >>= 1) lsum += __shfl_down(lsum, off, 64);
  if ((t & 63) == 0) wsum[t >> 6] = lsum;
  __syncthreads();  // also publishes hist[] and ridx[]
  if (t == 0) atomicAdd(ws, (wsum[0] + wsum[1]) + (wsum[2] + wsum[3]));

  unsigned* counts = (unsigned*)ws + 1;
  atomicAdd(&counts[t],       hist[t]);
  atomicAdd(&counts[t + 256], hist[t + 256]);

  // encodings: 256 rows x 512 floats per block, one-hot. float2 stores
  // (O_ENC is only 8-byte aligned). Coalesced: consecutive threads write
  // consecutive float2.
  float2* enc = (float2*)(out + O_ENC) + (size_t)blk * (256 * 256);
  for (int i = t; i < 256 * 256; i += 256) {
    const int r  = i >> 8;        // row (local pixel)
    const int c2 = i & 255;       // float2 index within row
    const unsigned bv = ridx[r];
    float2 v = make_float2(0.0f, 0.0f);
    if ((int)(bv >> 1) == c2) {
      if (bv & 1) v.y = 1.0f; else v.x = 1.0f;
    }
    enc[i] = v;
  }
}

// Finalize: perplexity from counts (exact: counts/2^17), loss mean.
__global__ void vq_fin(float* __restrict__ out, const float* __restrict__ ws) {
  __shared__ float red[8];
  const int t = threadIdx.x;  // 512
  const unsigned* counts = (const unsigned*)ws + 1;
  const float p = (float)counts[t] * (1.0f / 131072.0f);
  float h = p * logf(p + 1e-10f);
#pragma unroll
  for (int off = 32; off > 0; off >>= 1) h += __shfl_down(h, off, 64);
  if ((t & 63) == 0) red[t >> 6] = h;
  __syncthreads();
  if (t == 0) {
    float H = 0.0f;
#pragma unroll
    for (int w = 0; w < 8; ++w) H += red[w];
    out[O_PERP] = expf(-H);
    out[0] = 1.25f * ws[0] * (1.0f / 8388608.0f);
  }
}

extern "C" void kernel_launch(void* const* d_in, const int* in_sizes, int n_in,
                              void* d_out, int out_size, void* d_ws, size_t ws_size,
                              hipStream_t stream) {
  const float* z   = (const float*)d_in[0];
  const float* emb = (const float*)d_in[1];
  float* out = (float*)d_out;
  float* ws  = (float*)d_ws;

  vq_prep<<<1, 512, 0, stream>>>(emb, ws);
  vq_main<<<512, 256, 0, stream>>>(z, emb, out, ws);
  vq_fin<<<1, 512, 0, stream>>>(out, ws);
}